// Round 1
// baseline (240.284 us; speedup 1.0000x reference)
//
#include <hip/hip_runtime.h>

using short8  = __attribute__((ext_vector_type(8))) short;
using floatx4 = __attribute__((ext_vector_type(4))) float;

#define NB   8192
#define DIN  256
#define DE   128
#define NEX  16384
#define ND   64
#define ESPLIT 8
#define TE   64
#define BM   128
#define EPB  (NEX/ESPLIT)   // 2048 exemplars per block
#define NTIL (EPB/TE)       // 32 tiles
#define GAMMA_N 3.6787944117144233e-06f  // exp(-1)/100000

__device__ __forceinline__ unsigned short f2bf(float f) {
  unsigned int u = __float_as_uint(f);
  u += 0x7fffu + ((u >> 16) & 1u);      // round-to-nearest-even
  return (unsigned short)(u >> 16);
}
__device__ __forceinline__ float bf2f(unsigned short h) {
  return __uint_as_float(((unsigned int)h) << 16);
}

// ---------------- encoder: phi = x@W + b (f32), store bf16 + |phi_bf|^2 ----
__global__ __launch_bounds__(128) void k_encoder(
    const float* __restrict__ x, const float* __restrict__ W,
    const float* __restrict__ bias, unsigned short* __restrict__ phi_bf,
    float* __restrict__ pn)
{
  __shared__ float xs[8 * DIN];
  __shared__ float part[8][2];
  const int rb = blockIdx.x * 8;
  const int j  = threadIdx.x;            // 0..127 (output dim)
  #pragma unroll
  for (int i = 0; i < 16; ++i)
    xs[i * 128 + j] = x[rb * DIN + i * 128 + j];
  __syncthreads();
  float acc[8];
  const float bj = bias[j];
  #pragma unroll
  for (int r = 0; r < 8; ++r) acc[r] = bj;
  for (int k = 0; k < DIN; ++k) {
    const float wv = W[k * DE + j];
    #pragma unroll
    for (int r = 0; r < 8; ++r)
      acc[r] = fmaf(xs[r * DIN + k], wv, acc[r]);
  }
  #pragma unroll
  for (int r = 0; r < 8; ++r) {
    const unsigned short hb = f2bf(acc[r]);
    phi_bf[(rb + r) * DE + j] = hb;
    const float hf = bf2f(hb);
    float sq = hf * hf;
    #pragma unroll
    for (int off = 1; off < 64; off <<= 1) sq += __shfl_xor(sq, off, 64);
    if ((j & 63) == 0) part[r][j >> 6] = sq;
  }
  __syncthreads();
  if (j < 8) pn[rb + j] = part[j][0] + part[j][1];
}

// ---------------- exemplar prep: bf16 copy + |E_bf|^2 ---------------------
__global__ __launch_bounds__(128) void k_prep_e(
    const float* __restrict__ E, unsigned short* __restrict__ E_bf,
    float* __restrict__ en)
{
  __shared__ float part[2];
  const int e = blockIdx.x;
  const int j = threadIdx.x;
  const unsigned short hb = f2bf(E[e * DE + j]);
  E_bf[e * DE + j] = hb;
  const float hf = bf2f(hb);
  float sq = hf * hf;
  #pragma unroll
  for (int off = 1; off < 64; off <<= 1) sq += __shfl_xor(sq, off, 64);
  if ((j & 63) == 0) part[j >> 6] = sq;
  __syncthreads();
  if (j == 0) en[e] = part[0] + part[1];
}

// ---------------- KM curves: per-exemplar survival (wave64 scans) ---------
__global__ __launch_bounds__(256) void k_prep_km(
    const float* __restrict__ lev, const float* __restrict__ lcen,
    const float* __restrict__ lh, unsigned short* __restrict__ KM_bf,
    float* __restrict__ baseKM)
{
  const int t  = threadIdx.x & 63;
  const int wv = threadIdx.x >> 6;
  const int e  = blockIdx.x * 4 + wv;
  const float ev = __expf(lev[e * ND + t]);
  const float cn = __expf(lcen[e * ND + t]);
  float s = ev + cn;
  #pragma unroll
  for (int off = 1; off < 64; off <<= 1) {           // inclusive suffix sum
    const float o = __shfl(s, (t + off) & 63, 64);
    s += (t + off < 64) ? o : 0.0f;
  }
  const float haz = (s > 0.0f) ? (ev / s) : 0.0f;
  float lc = __logf(1.0f - haz + 1e-7f);
  #pragma unroll
  for (int off = 1; off < 64; off <<= 1) {           // inclusive prefix sum
    const float o = __shfl(lc, (t - off) & 63, 64);
    lc += (t >= off) ? o : 0.0f;
  }
  KM_bf[e * ND + t] = f2bf(__expf(lc));
  if (blockIdx.x == 0 && wv == 0) {                  // baseline KM
    const float h = 1.0f / (1.0f + __expf(-lh[t]));
    float l2 = __logf(1.0f - h + 1e-7f);
    #pragma unroll
    for (int off = 1; off < 64; off <<= 1) {
      const float o = __shfl(l2, (t - off) & 63, 64);
      l2 += (t >= off) ? o : 0.0f;
    }
    baseKM[t] = __expf(l2);
  }
}

// ---------------- fused: S=phi@E^T -> kw -> numer += kw@KM, denom += kw ---
__global__ __launch_bounds__(256) void k_fused(
    const unsigned short* __restrict__ phi_bf, const float* __restrict__ pn,
    const unsigned short* __restrict__ E_bf, const float* __restrict__ en,
    const unsigned short* __restrict__ KM_bf,
    float* __restrict__ numer_acc, float* __restrict__ denom_acc)
{
  __shared__ __align__(16) unsigned short E_lds[TE * 136];  // pad 8 -> stride 17x16B
  __shared__ __align__(16) unsigned short KMt[ND * 72];     // transposed [t][e], pad 8
  __shared__ __align__(16) unsigned short kw_lds[BM * 72];  // [row][e], pad 8
  __shared__ float en_lds[TE];

  const int tid = threadIdx.x;
  const int w   = tid >> 6;     // wave 0..3 -> 32-row slice
  const int l   = tid & 63;
  const int lr  = l & 15;       // fragment row/col lane
  const int g   = l >> 4;       // k-group
  const int rowbase = blockIdx.y * BM + w * 32;
  const int ebase0  = blockIdx.x * EPB;

  // loop-invariant A fragments (phi) and row norms at C-layout positions
  short8 af[2][4];
  float  pnf[2][4];
  #pragma unroll
  for (int m = 0; m < 2; ++m) {
    const int r = rowbase + m * 16 + lr;
    #pragma unroll
    for (int kq = 0; kq < 4; ++kq)
      af[m][kq] = *reinterpret_cast<const short8*>(phi_bf + r * DE + kq * 32 + g * 8);
    #pragma unroll
    for (int rg = 0; rg < 4; ++rg)
      pnf[m][rg] = pn[rowbase + m * 16 + g * 4 + rg];
  }

  floatx4 c2[2][4];
  float   dn[2][4];
  #pragma unroll
  for (int m = 0; m < 2; ++m) {
    #pragma unroll
    for (int n = 0; n < 4; ++n) c2[m][n] = (floatx4){0.f, 0.f, 0.f, 0.f};
    #pragma unroll
    for (int rg = 0; rg < 4; ++rg) dn[m][rg] = 0.f;
  }

  for (int it = 0; it < NTIL; ++it) {
    const int ebase = ebase0 + it * TE;
    __syncthreads();                       // protect LDS from previous tile's readers
    {                                      // stage E tile [64][128] bf16
      int erow = tid >> 4;
      const int c16 = (tid & 15) * 8;
      #pragma unroll
      for (int p = 0; p < 4; ++p, erow += 16)
        *reinterpret_cast<short8*>(&E_lds[erow * 136 + c16]) =
          *reinterpret_cast<const short8*>(E_bf + (ebase + erow) * DE + c16);
    }
    {                                      // stage KM tile transposed -> [t][e]
      const int tt = tid & 63;
      const int e0 = (tid >> 6) * 16;
      #pragma unroll
      for (int p = 0; p < 16; ++p) {
        const int e = e0 + p;
        KMt[tt * 72 + e] = KM_bf[(ebase + e) * ND + tt];
      }
    }
    if (tid < TE) en_lds[tid] = en[ebase + tid];
    __syncthreads();

    // GEMM1: S = phi @ E^T (K = 128), then kw = thresholded exp(-d2)
    #pragma unroll
    for (int n = 0; n < 4; ++n) {
      short8 bfr[4];
      #pragma unroll
      for (int kq = 0; kq < 4; ++kq)
        bfr[kq] = *reinterpret_cast<const short8*>(&E_lds[(n * 16 + lr) * 136 + kq * 32 + g * 8]);
      floatx4 s0 = (floatx4){0.f, 0.f, 0.f, 0.f};
      floatx4 s1 = (floatx4){0.f, 0.f, 0.f, 0.f};
      #pragma unroll
      for (int kq = 0; kq < 4; ++kq) {
        s0 = __builtin_amdgcn_mfma_f32_16x16x32_bf16(af[0][kq], bfr[kq], s0, 0, 0, 0);
        s1 = __builtin_amdgcn_mfma_f32_16x16x32_bf16(af[1][kq], bfr[kq], s1, 0, 0, 0);
      }
      const float env = en_lds[n * 16 + lr];
      #pragma unroll
      for (int m = 0; m < 2; ++m) {
        const floatx4 sv = m ? s1 : s0;
        #pragma unroll
        for (int rg = 0; rg < 4; ++rg) {
          float d2 = pnf[m][rg] + env - 2.0f * sv[rg];
          d2 = fmaxf(d2, 0.0f);
          const float kwv = (d2 <= 1.0f) ? __expf(-d2) : 0.0f;
          dn[m][rg] += kwv;
          kw_lds[(w * 32 + m * 16 + g * 4 + rg) * 72 + (n * 16 + lr)] = f2bf(kwv);
        }
      }
    }

    // GEMM2: numer += kw @ KM (contract over 64 exemplars, 2 K-steps)
    // kw rows are wave-private: no barrier needed (same-wave LDS RAW).
    short8 b2[4][2];
    #pragma unroll
    for (int n = 0; n < 4; ++n)
      #pragma unroll
      for (int kq = 0; kq < 2; ++kq)
        b2[n][kq] = *reinterpret_cast<const short8*>(&KMt[(n * 16 + lr) * 72 + kq * 32 + g * 8]);
    #pragma unroll
    for (int m = 0; m < 2; ++m) {
      short8 a2[2];
      #pragma unroll
      for (int kq = 0; kq < 2; ++kq)
        a2[kq] = *reinterpret_cast<const short8*>(&kw_lds[(w * 32 + m * 16 + lr) * 72 + kq * 32 + g * 8]);
      #pragma unroll
      for (int n = 0; n < 4; ++n)
        #pragma unroll
        for (int kq = 0; kq < 2; ++kq)
          c2[m][n] = __builtin_amdgcn_mfma_f32_16x16x32_bf16(a2[kq], b2[n][kq], c2[m][n], 0, 0, 0);
    }
  }

  // epilogue: denominator (reduce kw row-sums over the 16 col-lanes) + numer
  #pragma unroll
  for (int m = 0; m < 2; ++m)
    #pragma unroll
    for (int rg = 0; rg < 4; ++rg) {
      float v = dn[m][rg];
      v += __shfl_xor(v, 1, 64);
      v += __shfl_xor(v, 2, 64);
      v += __shfl_xor(v, 4, 64);
      v += __shfl_xor(v, 8, 64);
      if (lr == 0)
        atomicAdd(&denom_acc[rowbase + m * 16 + g * 4 + rg], v);
    }
  #pragma unroll
  for (int m = 0; m < 2; ++m)
    #pragma unroll
    for (int n = 0; n < 4; ++n)
      #pragma unroll
      for (int rg = 0; rg < 4; ++rg)
        atomicAdd(&numer_acc[(rowbase + m * 16 + g * 4 + rg) * ND + n * 16 + lr],
                  c2[m][n][rg]);
}

// ---------------- finalize ------------------------------------------------
__global__ __launch_bounds__(256) void k_finalize(
    const float* __restrict__ numer_acc, const float* __restrict__ denom_acc,
    const float* __restrict__ baseKM, float* __restrict__ out)
{
  const int idx = blockIdx.x * 256 + threadIdx.x;
  const int b = idx >> 6;
  const int t = idx & 63;
  const float num = numer_acc[idx] + GAMMA_N * baseKM[t];
  const float den = denom_acc[b] + GAMMA_N + 1e-12f;
  float r = num / den;
  r = fminf(fmaxf(r, 1e-12f), 1.0f - 1e-12f);
  out[idx] = r;
}

extern "C" void kernel_launch(void* const* d_in, const int* in_sizes, int n_in,
                              void* d_out, int out_size, void* d_ws, size_t ws_size,
                              hipStream_t stream)
{
  const float* x    = (const float*)d_in[0];
  const float* W    = (const float*)d_in[1];
  const float* bias = (const float*)d_in[2];
  const float* E    = (const float*)d_in[3];
  const float* lev  = (const float*)d_in[4];
  const float* lcen = (const float*)d_in[5];
  const float* lh   = (const float*)d_in[6];
  float* out = (float*)d_out;

  char* ws = (char*)d_ws;
  size_t off = 0;
  auto alloc = [&](size_t bytes) -> void* {
    void* p = ws + off;
    off += (bytes + 255) & ~(size_t)255;
    return p;
  };
  unsigned short* phi_bf = (unsigned short*)alloc((size_t)NB * DE * 2);
  unsigned short* E_bf   = (unsigned short*)alloc((size_t)NEX * DE * 2);
  unsigned short* KM_bf  = (unsigned short*)alloc((size_t)NEX * ND * 2);
  float* pn        = (float*)alloc((size_t)NB * 4);
  float* en        = (float*)alloc((size_t)NEX * 4);
  float* baseKM    = (float*)alloc((size_t)ND * 4);
  float* numer_acc = (float*)alloc((size_t)NB * ND * 4);
  float* denom_acc = (float*)alloc((size_t)NB * 4);

  hipMemsetAsync(numer_acc, 0, (size_t)NB * ND * 4, stream);
  hipMemsetAsync(denom_acc, 0, (size_t)NB * 4, stream);

  k_encoder<<<NB / 8, 128, 0, stream>>>(x, W, bias, phi_bf, pn);
  k_prep_e<<<NEX, 128, 0, stream>>>(E, E_bf, en);
  k_prep_km<<<NEX / 4, 256, 0, stream>>>(lev, lcen, lh, KM_bf, baseKM);
  k_fused<<<dim3(ESPLIT, NB / BM), 256, 0, stream>>>(phi_bf, pn, E_bf, en, KM_bf,
                                                     numer_acc, denom_acc);
  k_finalize<<<(NB * ND) / 256, 256, 0, stream>>>(numer_acc, denom_acc, baseKM, out);
}